// Round 2
// baseline (1506.436 us; speedup 1.0000x reference)
//
#include <hip/hip_runtime.h>
#include <math.h>

#define HW 25600
#define IMGW 160
#define CDIM 256
#define NB 4
#define NHEADS 8

// ---------------------------------------------------------------------------
// conv1x1 as GEMM: out[b][co][n] = sum_ci w[b][co][ci] * x[b][ci][n]
// tile: 128 co x 128 n, BK=32, 256 threads, 8x8 microtile per thread.
// Strides allow batched (grid.z>1) or single-batch (grid.z=1) use.
// ---------------------------------------------------------------------------
__global__ __launch_bounds__(256) void conv1x1_k(
    const float* __restrict__ x, const float* __restrict__ w,
    float* __restrict__ out,
    long xbstride, long wbstride, long obstride)
{
    __shared__ float xs[32 * 140];   // [kk][pos(n)], pos(n)=n+4*(n>>5)
    __shared__ float wst[32 * 132];  // [kk][co]
    const int t  = threadIdx.x;
    const int n0 = blockIdx.x * 128;
    const int co0 = blockIdx.y * 128;
    const int b  = blockIdx.z;
    const float* xb = x + (long)b * xbstride + n0;
    const float* wb = w + (long)b * wbstride + (long)co0 * CDIM;
    float* ob = out + (long)b * obstride + (long)co0 * HW + n0;

    float acc[8][8];
#pragma unroll
    for (int i = 0; i < 8; ++i)
#pragma unroll
        for (int j = 0; j < 8; ++j) acc[i][j] = 0.f;

    const int tn = t & 15;          // n-group: n = tn*8 .. tn*8+7
    const int cb = (t >> 4) * 8;    // co base within tile

    for (int kc = 0; kc < CDIM; kc += 32) {
        __syncthreads();
        // stage x tile [32][128] (swizzled columns)
#pragma unroll
        for (int r = 0; r < 4; ++r) {
            int idx = r * 1024 + t * 4;
            int kk = idx >> 7;
            int nn = idx & 127;
            float4 v = *(const float4*)(xb + (long)(kc + kk) * HW + nn);
            int pos = nn + 4 * (nn >> 5);
            *(float4*)(&xs[kk * 140 + pos]) = v;
        }
        // stage w tile transposed -> [kk][co]
#pragma unroll
        for (int r = 0; r < 4; ++r) {
            int idx = r * 1024 + t * 4;
            int rr = idx >> 5;
            int cc = idx & 31;
            float4 v = *(const float4*)(wb + (long)rr * CDIM + kc + cc);
            wst[(cc + 0) * 132 + rr] = v.x;
            wst[(cc + 1) * 132 + rr] = v.y;
            wst[(cc + 2) * 132 + rr] = v.z;
            wst[(cc + 3) * 132 + rr] = v.w;
        }
        __syncthreads();
#pragma unroll 4
        for (int kk = 0; kk < 32; ++kk) {
            float a[8], bv[8];
            const int apos = kk * 132 + cb;
            *(float4*)&a[0] = *(const float4*)&wst[apos];
            *(float4*)&a[4] = *(const float4*)&wst[apos + 4];
            const int c0 = tn * 8;
            const int bpos = kk * 140 + c0 + 4 * (tn >> 2);
            *(float4*)&bv[0] = *(const float4*)&xs[bpos];
            *(float4*)&bv[4] = *(const float4*)&xs[bpos + 4];
#pragma unroll
            for (int i = 0; i < 8; ++i)
#pragma unroll
                for (int j = 0; j < 8; ++j)
                    acc[i][j] = fmaf(a[i], bv[j], acc[i][j]);
        }
    }
#pragma unroll
    for (int i = 0; i < 8; ++i) {
        float4 v0 = make_float4(acc[i][0], acc[i][1], acc[i][2], acc[i][3]);
        float4 v1 = make_float4(acc[i][4], acc[i][5], acc[i][6], acc[i][7]);
        *(float4*)(ob + (long)(cb + i) * HW + tn * 8)     = v0;
        *(float4*)(ob + (long)(cb + i) * HW + tn * 8 + 4) = v1;
    }
}

// ---------------------------------------------------------------------------
// depthwise 3x3, pad 1. single batch group: x[c][HW], w[c][9], out[c][HW]
// grid: (HW/256, nchannels)
// ---------------------------------------------------------------------------
__global__ __launch_bounds__(256) void dwconv_k(
    const float* __restrict__ x, const float* __restrict__ w,
    float* __restrict__ out)
{
    int t = threadIdx.x;
    int n = blockIdx.x * 256 + t;
    int c = blockIdx.y;
    const float* xp = x + (long)c * HW;
    const float* wp = w + c * 9;
    int y  = n / IMGW;
    int xx = n - y * IMGW;
    float s = 0.f;
#pragma unroll
    for (int dy = -1; dy <= 1; ++dy) {
        int yy = y + dy;
        if (yy < 0 || yy >= IMGW) continue;
#pragma unroll
        for (int dx = -1; dx <= 1; ++dx) {
            int xn = xx + dx;
            if (xn < 0 || xn >= IMGW) continue;
            s += wp[(dy + 1) * 3 + (dx + 1)] * xp[yy * IMGW + xn];
        }
    }
    out[(long)c * HW + n] = s;
}

// ---------------------------------------------------------------------------
// gram partials (single batch): per (h,chunk): S[ci][cj] = sum_n q[ci,n]k[cj,n]
// plus per-channel sumsq partials for q and k. chunk = 1024 pixels.
// q,k are dense [256, HW]. grid: (25, 8)
// ---------------------------------------------------------------------------
__global__ __launch_bounds__(256) void gram_k(
    const float* __restrict__ q, const float* __restrict__ k,
    float* __restrict__ part_qk, float* __restrict__ part_sq_q,
    float* __restrict__ part_sq_k, int b)
{
    __shared__ float qs[128 * 33];
    __shared__ float ks[128 * 33];
    int t = threadIdx.x;
    int chunk = blockIdx.x;   // 0..24
    int h = blockIdx.y;
    const float* qp = q + (long)(h * 32) * HW + chunk * 1024;
    const float* kp = k + (long)(h * 32) * HW + chunk * 1024;
    const int ci  = t >> 3;
    const int cj0 = (t & 7) * 4;
    float a0 = 0, a1 = 0, a2 = 0, a3 = 0;
    float sqq = 0, sk0 = 0, sk1 = 0, sk2 = 0, sk3 = 0;
    const int nn = t & 127;
    const int cr = t >> 7;   // 0/1
    for (int s0 = 0; s0 < 1024; s0 += 128) {
        __syncthreads();
#pragma unroll
        for (int c2 = 0; c2 < 32; c2 += 2) {
            qs[nn * 33 + c2 + cr] = qp[(long)(c2 + cr) * HW + s0 + nn];
            ks[nn * 33 + c2 + cr] = kp[(long)(c2 + cr) * HW + s0 + nn];
        }
        __syncthreads();
#pragma unroll 4
        for (int n2 = 0; n2 < 128; ++n2) {
            float qv = qs[n2 * 33 + ci];
            float k0 = ks[n2 * 33 + cj0 + 0];
            float k1 = ks[n2 * 33 + cj0 + 1];
            float k2 = ks[n2 * 33 + cj0 + 2];
            float k3 = ks[n2 * 33 + cj0 + 3];
            a0 = fmaf(qv, k0, a0);
            a1 = fmaf(qv, k1, a1);
            a2 = fmaf(qv, k2, a2);
            a3 = fmaf(qv, k3, a3);
            if (cj0 == 0) sqq = fmaf(qv, qv, sqq);
            if (ci == 0) {
                sk0 = fmaf(k0, k0, sk0);
                sk1 = fmaf(k1, k1, sk1);
                sk2 = fmaf(k2, k2, sk2);
                sk3 = fmaf(k3, k3, sk3);
            }
        }
    }
    long pb = ((long)(b * NHEADS + h) * 25 + chunk);
    *(float4*)(part_qk + pb * 1024 + t * 4) = make_float4(a0, a1, a2, a3);
    if ((t & 7) == 0) part_sq_q[pb * 32 + ci] = sqq;
    if (ci == 0) {
        part_sq_k[pb * 32 + cj0 + 0] = sk0;
        part_sq_k[pb * 32 + cj0 + 1] = sk1;
        part_sq_k[pb * 32 + cj0 + 2] = sk2;
        part_sq_k[pb * 32 + cj0 + 3] = sk3;
    }
}

// ---------------------------------------------------------------------------
// reduce partials -> normalize -> softmax -> W_eff = proj_w @ blockdiag(attn)
// one block per (b,h), grid 32
// ---------------------------------------------------------------------------
__global__ __launch_bounds__(256) void attn_weff_k(
    const float* __restrict__ part_qk, const float* __restrict__ part_sq_q,
    const float* __restrict__ part_sq_k, const float* __restrict__ proj_w,
    const float* __restrict__ temp, float* __restrict__ weff)
{
    __shared__ float at[32 * 33];
    __shared__ float nq[32], nk[32];
    int bh = blockIdx.x;
    int b = bh >> 3, h = bh & 7;
    int t = threadIdx.x;
    long pb0 = (long)bh * 25;
    float4 s = make_float4(0, 0, 0, 0);
    for (int c = 0; c < 25; ++c) {
        float4 v = *(const float4*)(part_qk + (pb0 + c) * 1024 + t * 4);
        s.x += v.x; s.y += v.y; s.z += v.z; s.w += v.w;
    }
    if (t < 32) {
        float a = 0;
        for (int c = 0; c < 25; ++c) a += part_sq_q[(pb0 + c) * 32 + t];
        nq[t] = fmaxf(sqrtf(a), 1e-12f);
    } else if (t < 64) {
        int j = t - 32;
        float a = 0;
        for (int c = 0; c < 25; ++c) a += part_sq_k[(pb0 + c) * 32 + j];
        nk[j] = fmaxf(sqrtf(a), 1e-12f);
    }
    __syncthreads();
    float tp = temp[h];
    int ci = t >> 3, cj0 = (t & 7) * 4;
    at[ci * 33 + cj0 + 0] = s.x / (nq[ci] * nk[cj0 + 0]) * tp;
    at[ci * 33 + cj0 + 1] = s.y / (nq[ci] * nk[cj0 + 1]) * tp;
    at[ci * 33 + cj0 + 2] = s.z / (nq[ci] * nk[cj0 + 2]) * tp;
    at[ci * 33 + cj0 + 3] = s.w / (nq[ci] * nk[cj0 + 3]) * tp;
    __syncthreads();
    if (t < 32) {
        float m = -1e30f;
        for (int j = 0; j < 32; ++j) m = fmaxf(m, at[t * 33 + j]);
        float ss = 0;
        for (int j = 0; j < 32; ++j) {
            float e = expf(at[t * 33 + j] - m);
            at[t * 33 + j] = e;
            ss += e;
        }
        float inv = 1.f / ss;
        for (int j = 0; j < 32; ++j) at[t * 33 + j] *= inv;
    }
    __syncthreads();
    // W_eff[b][co][h*32+cj] = sum_ci proj_w[co][h*32+ci] * attn[ci][cj]
    int co = t;
    float pw[32];
#pragma unroll
    for (int i2 = 0; i2 < 32; ++i2) pw[i2] = proj_w[(long)co * CDIM + h * 32 + i2];
    for (int j = 0; j < 32; ++j) {
        float a = 0;
#pragma unroll
        for (int i2 = 0; i2 < 32; ++i2) a = fmaf(pw[i2], at[i2 * 33 + j], a);
        weff[((long)b * CDIM + co) * CDIM + h * 32 + j] = a;
    }
}

// ---------------------------------------------------------------------------
extern "C" void kernel_launch(void* const* d_in, const int* in_sizes, int n_in,
                              void* d_out, int out_size, void* d_ws, size_t ws_size,
                              hipStream_t stream)
{
    const float* low    = (const float*)d_in[0];
    const float* high   = (const float*)d_in[1];
    const float* q_w    = (const float*)d_in[2];
    const float* q_dw   = (const float*)d_in[3];
    const float* kv_w   = (const float*)d_in[4];
    const float* kv_dw  = (const float*)d_in[5];
    const float* proj_w = (const float*)d_in[6];
    const float* temp   = (const float*)d_in[7];
    float* out = (float*)d_out;
    float* ws  = (float*)d_ws;

    const long SZB = (long)CDIM * HW;          // 6,553,600 floats (one batch, 256 ch)

    // workspace layout (floats)
    float* v_full  = ws;                       // [4][256][HW]  = 4*SZB
    float* A       = v_full + 4 * SZB;         // [512][HW]     = 2*SZB  (kvpre_b / qpre_b)
    float* Bk      = A + 2 * SZB;              // [256][HW]     = SZB    (k_b)
    float* Cq      = Bk + SZB;                 // [256][HW]     = SZB    (q_b)
    float* part_qk   = Cq + SZB;               // 32*25*1024
    float* part_sq_q = part_qk + 32L * 25 * 1024;
    float* part_sq_k = part_sq_q + 32L * 25 * 32;
    float* weff      = part_sq_k + 32L * 25 * 32;   // [4][256][256]
    const long total = (weff - ws) + 4L * CDIM * CDIM;
    if (ws_size < (size_t)total * sizeof(float)) return;  // avoid OOB fault

    dim3 blk(256);

    for (int b = 0; b < NB; ++b) {
        const float* low_b  = low  + (long)b * SZB;
        const float* high_b = high + (long)b * SZB;
        // 1. A = conv1x1(low_b, kv_w)  [512, HW]
        conv1x1_k<<<dim3(200, 4, 1), blk, 0, stream>>>(low_b, kv_w, A, 0, 0, 0);
        // 2. k_b = dwconv(A[0:256]);  v[b] = dwconv(A[256:512])
        dwconv_k<<<dim3(100, 256), blk, 0, stream>>>(A, kv_dw, Bk);
        dwconv_k<<<dim3(100, 256), blk, 0, stream>>>(A + 256L * HW, kv_dw + 256 * 9,
                                                     v_full + (long)b * SZB);
        // 3. A[0:256] = conv1x1(high_b, q_w)
        conv1x1_k<<<dim3(200, 2, 1), blk, 0, stream>>>(high_b, q_w, A, 0, 0, 0);
        // 4. q_b = dwconv(A[0:256])
        dwconv_k<<<dim3(100, 256), blk, 0, stream>>>(A, q_dw, Cq);
        // 5. gram partials for batch b
        gram_k<<<dim3(25, NHEADS), blk, 0, stream>>>(Cq, Bk, part_qk, part_sq_q,
                                                     part_sq_k, b);
    }

    // 6. softmax + W_eff = proj_w @ blockdiag(attn)
    attn_weff_k<<<dim3(32), blk, 0, stream>>>(
        part_qk, part_sq_q, part_sq_k, proj_w, temp, weff);

    // 7. out[b] = W_eff[b] @ v[b]   (batched)
    conv1x1_k<<<dim3(200, 2, NB), blk, 0, stream>>>(
        v_full, weff, out, SZB, (long)CDIM * CDIM, SZB);
}

// Round 5
// 480.769 us; speedup vs baseline: 3.1334x; 3.1334x over previous
//
#include <hip/hip_runtime.h>
#include <math.h>

#define HW 25600
#define IMGW 160
#define CDIM 256
#define NB 4
#define NHEADS 8

typedef __attribute__((ext_vector_type(8))) short short8v;
typedef __attribute__((ext_vector_type(4))) float f32x4;
typedef __attribute__((ext_vector_type(8))) unsigned short us8;

union FragU {
    us8 o;
    short8v s;
};

__device__ inline unsigned short f2bf(float f) {
    unsigned u = __float_as_uint(f);
    return (unsigned short)((u + 0x7fffu + ((u >> 16) & 1u)) >> 16);
}
__device__ inline float bf2f(unsigned short h) {
    return __uint_as_float(((unsigned)h) << 16);
}

// ---------------------------------------------------------------------------
// fp32 -> bf16 convert (plain, for weights)
// ---------------------------------------------------------------------------
__global__ __launch_bounds__(256) void cvt_k(
    const float* __restrict__ x, unsigned short* __restrict__ y, long n)
{
    long i = ((long)blockIdx.x * 256 + threadIdx.x) * 8;
    if (i >= n) return;
    float4 v0 = *(const float4*)(x + i);
    float4 v1 = *(const float4*)(x + i + 4);
    us8 o;
    o[0] = f2bf(v0.x); o[1] = f2bf(v0.y); o[2] = f2bf(v0.z); o[3] = f2bf(v0.w);
    o[4] = f2bf(v1.x); o[5] = f2bf(v1.y); o[6] = f2bf(v1.z); o[7] = f2bf(v1.w);
    *(us8*)(y + i) = o;
}

// ---------------------------------------------------------------------------
// fp32 [256][HW] -> bf16 transposed [HW][256]. 64x64 tiles via LDS.
// grid (HW/64, 256/64)
// ---------------------------------------------------------------------------
__global__ __launch_bounds__(256) void cvtT_k(
    const float* __restrict__ x, unsigned short* __restrict__ xt)
{
    __shared__ float tile[64][65];
    const int t = threadIdx.x;
    const int n0 = blockIdx.x * 64;
    const int c0 = blockIdx.y * 64;
#pragma unroll
    for (int it = 0; it < 4; ++it) {
        int row = (t >> 4) + it * 16;
        int col = (t & 15) * 4;
        float4 v = *(const float4*)(x + (long)(c0 + row) * HW + n0 + col);
        tile[row][col] = v.x; tile[row][col + 1] = v.y;
        tile[row][col + 2] = v.z; tile[row][col + 3] = v.w;
    }
    __syncthreads();
#pragma unroll
    for (int jt = 0; jt < 2; ++jt) {
        int nl = (t >> 3) + jt * 32;
        int cl = (t & 7) * 8;
        us8 o;
#pragma unroll
        for (int u = 0; u < 8; ++u) o[u] = f2bf(tile[cl + u][nl]);
        *(us8*)(xt + (long)(n0 + nl) * CDIM + c0 + cl) = o;
    }
}

// ---------------------------------------------------------------------------
// bf16 [256][HW] -> bf16 transposed [HW][256]. 64x64 tiles via LDS.
// ---------------------------------------------------------------------------
__global__ __launch_bounds__(256) void trT_k(
    const unsigned short* __restrict__ x, unsigned short* __restrict__ xt)
{
    __shared__ unsigned short tile[64][72];
    const int t = threadIdx.x;
    const int n0 = blockIdx.x * 64;
    const int c0 = blockIdx.y * 64;
#pragma unroll
    for (int it = 0; it < 2; ++it) {
        int row = (t >> 3) + it * 32;
        int col = (t & 7) * 8;
        us8 v = *(const us8*)(x + (long)(c0 + row) * HW + n0 + col);
        *(us8*)&tile[row][col] = v;
    }
    __syncthreads();
#pragma unroll
    for (int jt = 0; jt < 2; ++jt) {
        int nl = (t >> 3) + jt * 32;
        int cl = (t & 7) * 8;
        us8 o;
#pragma unroll
        for (int u = 0; u < 8; ++u) o[u] = tile[cl + u][nl];
        *(us8*)(xt + (long)(n0 + nl) * CDIM + c0 + cl) = o;
    }
}

// ---------------------------------------------------------------------------
// bf16 MFMA GEMM, B^T form: out[b][co][n] = sum_k W[b][co][k] * XT[b][n][k]
// Both operands k-contiguous. 128co x 128n tile, 4 waves, 16x16x32 MFMA.
// Both tiles reg-staged into pad-40 LDS rows; frags are contiguous us8 reads.
// k-slot map for BOTH A and B: slot(g,e) -> k = g*8+e (valid by symmetry).
// ---------------------------------------------------------------------------
template<int OUTF32>
__global__ __launch_bounds__(256) void gemm_bt(
    const unsigned short* __restrict__ XT, const unsigned short* __restrict__ W,
    void* __restrict__ outp, long xbs, long wbs, long obs)
{
    __shared__ __align__(16) unsigned short Ws[128 * 40];
    __shared__ __align__(16) unsigned short Bs[128 * 40];
    const int t  = threadIdx.x;
    const int l  = t & 63;
    const int wv = t >> 6;
    const int g  = l >> 4;
    const int ln = l & 15;
    const int n0  = blockIdx.x * 128;
    const int co0 = blockIdx.y * 128;
    const long b  = blockIdx.z;
    const unsigned short* Xb = XT + b * xbs;
    const unsigned short* Wb = W + b * wbs;
    const int wr = wv >> 1, wc = wv & 1;

    f32x4 acc[4][4];
#pragma unroll
    for (int i = 0; i < 4; ++i)
#pragma unroll
        for (int j = 0; j < 4; ++j) acc[i][j] = (f32x4){0.f, 0.f, 0.f, 0.f};

    const int srow = t >> 1;            // staged row (co or n) 0..127
    const int sko  = (t & 1) * 16;      // k-offset 0 / 16

    for (int kc = 0; kc < CDIM; kc += 32) {
        __syncthreads();
        {
            const unsigned short* wp = Wb + (long)(co0 + srow) * CDIM + kc + sko;
            us8 w0 = *(const us8*)wp;
            us8 w1 = *(const us8*)(wp + 8);
            *(us8*)&Ws[srow * 40 + sko]     = w0;
            *(us8*)&Ws[srow * 40 + sko + 8] = w1;
            const unsigned short* xp = Xb + (long)(n0 + srow) * CDIM + kc + sko;
            us8 x0 = *(const us8*)xp;
            us8 x1 = *(const us8*)(xp + 8);
            *(us8*)&Bs[srow * 40 + sko]     = x0;
            *(us8*)&Bs[srow * 40 + sko + 8] = x1;
        }
        __syncthreads();

        FragU A_[4], B_[4];
#pragma unroll
        for (int i = 0; i < 4; ++i)
            A_[i].o = *(const us8*)&Ws[(wr * 64 + i * 16 + ln) * 40 + g * 8];
#pragma unroll
        for (int j = 0; j < 4; ++j)
            B_[j].o = *(const us8*)&Bs[(wc * 64 + j * 16 + ln) * 40 + g * 8];
#pragma unroll
        for (int i = 0; i < 4; ++i)
#pragma unroll
            for (int j = 0; j < 4; ++j)
                acc[i][j] = __builtin_amdgcn_mfma_f32_16x16x32_bf16(
                    A_[i].s, B_[j].s, acc[i][j], 0, 0, 0);
    }

    // epilogue: D layout col=lane&15, row=(lane>>4)*4+reg  (m89-verified)
    if (OUTF32) {
        float* ob = (float*)outp + b * obs;
#pragma unroll
        for (int i = 0; i < 4; ++i)
#pragma unroll
            for (int j = 0; j < 4; ++j) {
                long ocol = n0 + wc * 64 + j * 16 + ln;
#pragma unroll
                for (int r = 0; r < 4; ++r) {
                    long orow = co0 + wr * 64 + i * 16 + g * 4 + r;
                    ob[orow * HW + ocol] = acc[i][j][r];
                }
            }
    } else {
        unsigned short* ob = (unsigned short*)outp + b * obs;
#pragma unroll
        for (int i = 0; i < 4; ++i)
#pragma unroll
            for (int j = 0; j < 4; ++j) {
                long ocol = n0 + wc * 64 + j * 16 + ln;
#pragma unroll
                for (int r = 0; r < 4; ++r) {
                    long orow = co0 + wr * 64 + i * 16 + g * 4 + r;
                    ob[orow * HW + ocol] = f2bf(acc[i][j][r]);
                }
            }
    }
}

// ---------------------------------------------------------------------------
// depthwise 3x3 bf16, pad 1, single batch-group. 8 px/thread. grid (13, C)
// ---------------------------------------------------------------------------
__global__ __launch_bounds__(256) void dwconv_k(
    const unsigned short* __restrict__ x, const float* __restrict__ w,
    unsigned short* __restrict__ out)
{
    int idx = blockIdx.x * 256 + threadIdx.x;
    if (idx >= 3200) return;
    int c = blockIdx.y;
    const unsigned short* xp = x + (long)c * HW;
    const float* wp = w + c * 9;
    int y  = idx / 20;
    int x0 = (idx % 20) * 8;
    float s[8];
#pragma unroll
    for (int p = 0; p < 8; ++p) s[p] = 0.f;
#pragma unroll
    for (int dy = -1; dy <= 1; ++dy) {
        int yy = y + dy;
        if (yy < 0 || yy >= IMGW) continue;
        const unsigned short* row = xp + yy * IMGW + x0;
        float r[10];
        r[0] = (x0 > 0) ? bf2f(row[-1]) : 0.f;
        us8 mid = *(const us8*)row;
#pragma unroll
        for (int p = 0; p < 8; ++p) r[1 + p] = bf2f(mid[p]);
        r[9] = (x0 + 8 < IMGW) ? bf2f(row[8]) : 0.f;
        float w0 = wp[(dy + 1) * 3 + 0];
        float w1 = wp[(dy + 1) * 3 + 1];
        float w2 = wp[(dy + 1) * 3 + 2];
#pragma unroll
        for (int p = 0; p < 8; ++p)
            s[p] = fmaf(w0, r[p], fmaf(w1, r[p + 1], fmaf(w2, r[p + 2], s[p])));
    }
    us8 o;
#pragma unroll
    for (int p = 0; p < 8; ++p) o[p] = f2bf(s[p]);
    *(us8*)(out + (long)c * HW + y * IMGW + x0) = o;
}

// ---------------------------------------------------------------------------
// gram via MFMA, direct global us8 frag loads (k-slot map g*8+e on both
// operands -> valid). grid (8 chunks, 8 heads), per batch.
// ---------------------------------------------------------------------------
__global__ __launch_bounds__(256) void gram_k(
    const unsigned short* __restrict__ q, const unsigned short* __restrict__ k,
    float* __restrict__ part_qk, float* __restrict__ part_sq_q,
    float* __restrict__ part_sq_k, int b)
{
    __shared__ float Sred[4 * 1024];
    __shared__ float sqq_l[4][32];
    __shared__ float sqk_l[4][32];
    const int t  = threadIdx.x;
    const int l  = t & 63;
    const int wv = t >> 6;
    const int g  = l >> 4;
    const int ln = l & 15;
    const int chunk = blockIdx.x;
    const int h = blockIdx.y;

    f32x4 accS[2][2], accQ[2], accK[2];
#pragma unroll
    for (int i = 0; i < 2; ++i) {
        accQ[i] = (f32x4){0, 0, 0, 0};
        accK[i] = (f32x4){0, 0, 0, 0};
#pragma unroll
        for (int j = 0; j < 2; ++j) accS[i][j] = (f32x4){0, 0, 0, 0};
    }

    const long rowq0 = (long)(h * 32) * HW;
    long nb = (long)chunk * 3200 + wv * 800;
    for (int s = 0; s < 25; ++s, nb += 32) {
        FragU aq[2], bk[2];
#pragma unroll
        for (int i = 0; i < 2; ++i)
            aq[i].o = *(const us8*)(q + rowq0 + (long)(i * 16 + ln) * HW + nb + g * 8);
#pragma unroll
        for (int j = 0; j < 2; ++j)
            bk[j].o = *(const us8*)(k + rowq0 + (long)(j * 16 + ln) * HW + nb + g * 8);
#pragma unroll
        for (int i = 0; i < 2; ++i)
#pragma unroll
            for (int j = 0; j < 2; ++j)
                accS[i][j] = __builtin_amdgcn_mfma_f32_16x16x32_bf16(
                    aq[i].s, bk[j].s, accS[i][j], 0, 0, 0);
#pragma unroll
        for (int i = 0; i < 2; ++i) {
            accQ[i] = __builtin_amdgcn_mfma_f32_16x16x32_bf16(
                aq[i].s, aq[i].s, accQ[i], 0, 0, 0);
            accK[i] = __builtin_amdgcn_mfma_f32_16x16x32_bf16(
                bk[i].s, bk[i].s, accK[i], 0, 0, 0);
        }
    }
#pragma unroll
    for (int i = 0; i < 2; ++i)
#pragma unroll
        for (int j = 0; j < 2; ++j)
#pragma unroll
            for (int r = 0; r < 4; ++r) {
                int row = i * 16 + g * 4 + r;
                int col = j * 16 + ln;
                Sred[wv * 1024 + row * 32 + col] = accS[i][j][r];
            }
#pragma unroll
    for (int i = 0; i < 2; ++i)
#pragma unroll
        for (int r = 0; r < 4; ++r)
            if (ln == g * 4 + r) {
                sqq_l[wv][i * 16 + g * 4 + r] = accQ[i][r];
                sqk_l[wv][i * 16 + g * 4 + r] = accK[i][r];
            }
    __syncthreads();
    const long pb = ((long)(b * NHEADS + h) * 8 + chunk);
#pragma unroll
    for (int e0 = 0; e0 < 4; ++e0) {
        int e = e0 * 256 + t;
        float v = Sred[e] + Sred[1024 + e] + Sred[2048 + e] + Sred[3072 + e];
        part_qk[pb * 1024 + e] = v;
    }
    if (t < 32)
        part_sq_q[pb * 32 + t] = sqq_l[0][t] + sqq_l[1][t] + sqq_l[2][t] + sqq_l[3][t];
    else if (t < 64) {
        int j = t - 32;
        part_sq_k[pb * 32 + j] = sqk_l[0][j] + sqk_l[1][j] + sqk_l[2][j] + sqk_l[3][j];
    }
}

// ---------------------------------------------------------------------------
// reduce partials -> normalize -> softmax -> W_eff = proj_w @ blockdiag(attn)
// one block per (b,h), grid 32. weff in bf16.
// ---------------------------------------------------------------------------
__global__ __launch_bounds__(256) void attn_weff_k(
    const float* __restrict__ part_qk, const float* __restrict__ part_sq_q,
    const float* __restrict__ part_sq_k, const float* __restrict__ proj_w,
    const float* __restrict__ temp, unsigned short* __restrict__ weff)
{
    __shared__ float at[32 * 33];
    __shared__ float nq[32], nk[32];
    int bh = blockIdx.x;
    int b = bh >> 3, h = bh & 7;
    int t = threadIdx.x;
    long pb0 = (long)bh * 8;
    float4 s = make_float4(0, 0, 0, 0);
    for (int c = 0; c < 8; ++c) {
        float4 v = *(const float4*)(part_qk + (pb0 + c) * 1024 + t * 4);
        s.x += v.x; s.y += v.y; s.z += v.z; s.w += v.w;
    }
    if (t < 32) {
        float a = 0;
        for (int c = 0; c < 8; ++c) a += part_sq_q[(pb0 + c) * 32 + t];
        nq[t] = fmaxf(sqrtf(a), 1e-12f);
    } else if (t < 64) {
        int j = t - 32;
        float a = 0;
        for (int c = 0; c < 8; ++c) a += part_sq_k[(pb0 + c) * 32 + j];
        nk[j] = fmaxf(sqrtf(a), 1e-12f);
    }
    __syncthreads();
    float tp = temp[h];
    int ci = t >> 3, cj0 = (t & 7) * 4;
    at[ci * 33 + cj0 + 0] = s.x / (nq[ci] * nk[cj0 + 0]) * tp;
    at[ci * 33 + cj0 + 1] = s.y / (nq[ci] * nk[cj0 + 1]) * tp;
    at[ci * 33 + cj0 + 2] = s.z / (nq[ci] * nk[cj0 + 2]) * tp;
    at[ci * 33 + cj0 + 3] = s.w / (nq[ci] * nk[cj0 + 3]) * tp;
    __syncthreads();
    if (t < 32) {
        float m = -1e30f;
        for (int j = 0; j < 32; ++j) m = fmaxf(m, at[t * 33 + j]);
        float ss = 0;
        for (int j = 0; j < 32; ++j) {
            float e = expf(at[t * 33 + j] - m);
            at[t * 33 + j] = e;
            ss += e;
        }
        float inv = 1.f / ss;
        for (int j = 0; j < 32; ++j) at[t * 33 + j] *= inv;
    }
    __syncthreads();
    int co = t;
    float pw[32];
#pragma unroll
    for (int i2 = 0; i2 < 32; ++i2) pw[i2] = proj_w[(long)co * CDIM + h * 32 + i2];
    for (int j = 0; j < 32; ++j) {
        float a = 0;
#pragma unroll
        for (int i2 = 0; i2 < 32; ++i2) a = fmaf(pw[i2], at[i2 * 33 + j], a);
        weff[((long)b * CDIM + co) * CDIM + h * 32 + j] = f2bf(a);
    }
}

// ---------------------------------------------------------------------------
extern "C" void kernel_launch(void* const* d_in, const int* in_sizes, int n_in,
                              void* d_out, int out_size, void* d_ws, size_t ws_size,
                              hipStream_t stream)
{
    const float* low    = (const float*)d_in[0];
    const float* high   = (const float*)d_in[1];
    const float* q_w    = (const float*)d_in[2];
    const float* q_dw   = (const float*)d_in[3];
    const float* kv_w   = (const float*)d_in[4];
    const float* kv_dw  = (const float*)d_in[5];
    const float* proj_w = (const float*)d_in[6];
    const float* temp   = (const float*)d_in[7];
    float* out = (float*)d_out;

    const long SZB = (long)CDIM * HW;   // 6,553,600 elems per [256][HW] buffer

    unsigned short* usws = (unsigned short*)d_ws;
    unsigned short* VT     = usws;                    // [4][HW][256]
    unsigned short* XT     = VT + 4 * SZB;            // [HW][256]
    unsigned short* A      = XT + SZB;                // [512][HW]
    unsigned short* Bk     = A + 2 * SZB;             // [256][HW]
    unsigned short* Cq     = Bk + SZB;                // [256][HW]
    unsigned short* v_cn   = Cq + SZB;                // [256][HW]
    unsigned short* wkv    = v_cn + SZB;              // [512][256]
    unsigned short* wq     = wkv + 512 * CDIM;        // [256][256]
    unsigned short* weff   = wq + CDIM * CDIM;        // [4][256][256]
    float* part_qk   = (float*)(weff + 4L * CDIM * CDIM);
    float* part_sq_q = part_qk + 32L * 8 * 1024;
    float* part_sq_k = part_sq_q + 32L * 8 * 32;
    float* endp      = part_sq_k + 32L * 8 * 32;
    size_t need = (size_t)((char*)endp - (char*)d_ws);
    if (ws_size < need) return;

    dim3 blk(256);

    // weights -> bf16 (once)
    cvt_k<<<dim3(64), blk, 0, stream>>>(kv_w, wkv, 512L * CDIM);
    cvt_k<<<dim3(32), blk, 0, stream>>>(q_w, wq, (long)CDIM * CDIM);

    for (int b = 0; b < NB; ++b) {
        // kv chain
        cvtT_k<<<dim3(400, 4), blk, 0, stream>>>(low + (long)b * SZB, XT);
        gemm_bt<0><<<dim3(200, 4, 1), blk, 0, stream>>>(XT, wkv, A, 0, 0, 0);
        dwconv_k<<<dim3(13, 256), blk, 0, stream>>>(A, kv_dw, Bk);
        dwconv_k<<<dim3(13, 256), blk, 0, stream>>>(A + 256L * HW, kv_dw + 256 * 9,
                                                    v_cn);
        trT_k<<<dim3(400, 4), blk, 0, stream>>>(v_cn, VT + (long)b * SZB);
        // q chain
        cvtT_k<<<dim3(400, 4), blk, 0, stream>>>(high + (long)b * SZB, XT);
        gemm_bt<0><<<dim3(200, 2, 1), blk, 0, stream>>>(XT, wq, A, 0, 0, 0);
        dwconv_k<<<dim3(13, 256), blk, 0, stream>>>(A, q_dw, Cq);
        // gram
        gram_k<<<dim3(8, NHEADS), blk, 0, stream>>>(Cq, Bk, part_qk, part_sq_q,
                                                    part_sq_k, b);
    }

    attn_weff_k<<<dim3(32), blk, 0, stream>>>(
        part_qk, part_sq_q, part_sq_k, proj_w, temp, weff);

    // out[b] = W_eff[b] @ v[b]  (VT is v^T per batch)
    gemm_bt<1><<<dim3(200, 2, NB), blk, 0, stream>>>(
        VT, weff, out, SZB, (long)CDIM * CDIM, SZB);
}

// Round 6
// 416.404 us; speedup vs baseline: 3.6177x; 1.1546x over previous
//
#include <hip/hip_runtime.h>
#include <math.h>

#define HW 25600
#define IMGW 160
#define CDIM 256
#define NB 4
#define NHEADS 8
#define SZB ((long)CDIM * HW)   // 6,553,600 elems

typedef __attribute__((ext_vector_type(8))) short short8v;
typedef __attribute__((ext_vector_type(4))) float f32x4;
typedef __attribute__((ext_vector_type(8))) unsigned short us8;

union FragU {
    us8 o;
    short8v s;
};

__device__ inline unsigned short f2bf(float f) {
    unsigned u = __float_as_uint(f);
    return (unsigned short)((u + 0x7fffu + ((u >> 16) & 1u)) >> 16);
}
__device__ inline float bf2f(unsigned short h) {
    return __uint_as_float(((unsigned)h) << 16);
}

// ---------------------------------------------------------------------------
// weights fp32 [co_off+co][256] -> swizzled bf16 [8kt][nco][32]
// slot(g2, co) = g2 ^ ((co>>1)&3)
// ---------------------------------------------------------------------------
__global__ __launch_bounds__(256) void cvtw_k(
    const float* __restrict__ w, unsigned short* __restrict__ o,
    int co_off, int nco)
{
    int idx = blockIdx.x * 256 + threadIdx.x;   // one us8 per thread
    if (idx >= nco * 32) return;                // nco * 8kt * 4g2
    int g2 = idx & 3;
    int kt = (idx >> 2) & 7;
    int co = idx >> 5;
    const float* src = w + (long)(co_off + co) * CDIM + kt * 32 + g2 * 8;
    us8 v;
#pragma unroll
    for (int u = 0; u < 8; ++u) v[u] = f2bf(src[u]);
    int slot = g2 ^ ((co >> 1) & 3);
    *(us8*)(o + ((long)kt * nco + co) * 32 + slot * 8) = v;
}

// ---------------------------------------------------------------------------
// fp32 [b][256][HW] -> swizzled-transposed bf16 XS [b][8kt][HW][32]
// grid (HW/64, 4, NB)
// ---------------------------------------------------------------------------
__global__ __launch_bounds__(256) void cvtT2_k(
    const float* __restrict__ x, unsigned short* __restrict__ xs)
{
    __shared__ float tile[64][65];
    const int t = threadIdx.x;
    const int n0 = blockIdx.x * 64;
    const int c0 = blockIdx.y * 64;
    const long b = blockIdx.z;
    const float* xb = x + b * SZB;
    unsigned short* xo = xs + b * SZB;
#pragma unroll
    for (int it = 0; it < 4; ++it) {
        int row = (t >> 4) + it * 16;     // c-local
        int col = (t & 15) * 4;           // n-local
        float4 v = *(const float4*)(xb + (long)(c0 + row) * HW + n0 + col);
        tile[row][col]     = v.x; tile[row][col + 1] = v.y;
        tile[row][col + 2] = v.z; tile[row][col + 3] = v.w;
    }
    __syncthreads();
#pragma unroll
    for (int jt = 0; jt < 2; ++jt) {
        int nl = (t >> 3) + jt * 32;
        int cl = (t & 7) * 8;
        us8 o;
#pragma unroll
        for (int u = 0; u < 8; ++u) o[u] = f2bf(tile[cl + u][nl]);
        int n  = n0 + nl;
        int c  = c0 + cl;
        int kt = c >> 5;
        int g2 = (c >> 3) & 3;
        int slot = g2 ^ ((n >> 1) & 3);
        *(us8*)(xo + ((long)kt * HW + n) * 32 + slot * 8) = o;
    }
}

// ---------------------------------------------------------------------------
// bf16 MFMA GEMM v2: out[b][co][n] = sum_k W[co][k] * X[k][n]
// Operands in swizzled [kt][row][32] layout; staged via global_load_lds
// width=16 into LINEAR LDS; frag reads apply the inverse swizzle (b128).
// 128x128 tile, 4 waves, 16x16x32 MFMA.
// ---------------------------------------------------------------------------
template<int OUTF32>
__global__ __launch_bounds__(256) void gemm2_k(
    const unsigned short* __restrict__ XS, const unsigned short* __restrict__ WS,
    void* __restrict__ outp, long xbs, long wbs, long obs, int nco)
{
    __shared__ __align__(16) unsigned short Wl[128 * 32];
    __shared__ __align__(16) unsigned short Xl[128 * 32];
    const int t  = threadIdx.x;
    const int l  = t & 63;
    const int wv = t >> 6;
    const int g  = l >> 4;
    const int ln = l & 15;
    const int n0  = blockIdx.x * 128;
    const int co0 = blockIdx.y * 128;
    const long b  = blockIdx.z;
    const unsigned short* Xb = XS + b * xbs;
    const unsigned short* Wb = WS + b * wbs;
    const int wr = wv >> 1, wc = wv & 1;

    f32x4 acc[4][4];
#pragma unroll
    for (int i = 0; i < 4; ++i)
#pragma unroll
        for (int j = 0; j < 4; ++j) acc[i][j] = (f32x4){0.f, 0.f, 0.f, 0.f};

    const int lrow = l >> 2;     // glds: lane covers row (instr*16 + lrow)
    const int lgrp = l & 3;      // 16B group

    for (int kt = 0; kt < 8; ++kt) {
        __syncthreads();
#pragma unroll
        for (int ii = 0; ii < 2; ++ii) {
            int instr = wv * 2 + ii;
            int row = instr * 16 + lrow;
            const unsigned short* wsrc =
                Wb + ((long)kt * nco + co0 + row) * 32 + lgrp * 8;
            __builtin_amdgcn_global_load_lds(
                (const __attribute__((address_space(1))) void*)wsrc,
                (__attribute__((address_space(3))) void*)&Wl[instr * 512], 16, 0, 0);
            const unsigned short* xsrc =
                Xb + ((long)kt * HW + n0 + row) * 32 + lgrp * 8;
            __builtin_amdgcn_global_load_lds(
                (const __attribute__((address_space(1))) void*)xsrc,
                (__attribute__((address_space(3))) void*)&Xl[instr * 512], 16, 0, 0);
        }
        __syncthreads();

        FragU A_[4], B_[4];
#pragma unroll
        for (int i = 0; i < 4; ++i) {
            int row = wr * 64 + i * 16 + ln;
            int slot = g ^ ((row >> 1) & 3);
            A_[i].o = *(const us8*)&Wl[row * 32 + slot * 8];
        }
#pragma unroll
        for (int j = 0; j < 4; ++j) {
            int row = wc * 64 + j * 16 + ln;
            int slot = g ^ ((row >> 1) & 3);
            B_[j].o = *(const us8*)&Xl[row * 32 + slot * 8];
        }
#pragma unroll
        for (int i = 0; i < 4; ++i)
#pragma unroll
            for (int j = 0; j < 4; ++j)
                acc[i][j] = __builtin_amdgcn_mfma_f32_16x16x32_bf16(
                    A_[i].s, B_[j].s, acc[i][j], 0, 0, 0);
    }

    // epilogue: D layout col=lane&15, row=(lane>>4)*4+reg (HW-verified)
    if (OUTF32) {
        float* ob = (float*)outp + b * obs;
#pragma unroll
        for (int i = 0; i < 4; ++i)
#pragma unroll
            for (int j = 0; j < 4; ++j) {
                long ocol = n0 + wc * 64 + j * 16 + ln;
#pragma unroll
                for (int r = 0; r < 4; ++r) {
                    long orow = co0 + wr * 64 + i * 16 + g * 4 + r;
                    ob[orow * HW + ocol] = acc[i][j][r];
                }
            }
    } else {
        unsigned short* ob = (unsigned short*)outp + b * obs;
#pragma unroll
        for (int i = 0; i < 4; ++i)
#pragma unroll
            for (int j = 0; j < 4; ++j) {
                long ocol = n0 + wc * 64 + j * 16 + ln;
#pragma unroll
                for (int r = 0; r < 4; ++r) {
                    long orow = co0 + wr * 64 + i * 16 + g * 4 + r;
                    ob[orow * HW + ocol] = f2bf(acc[i][j][r]);
                }
            }
    }
}

// ---------------------------------------------------------------------------
// depthwise 3x3 bf16, tiled 32n x 64c, batched. TRANSPOSED=1 writes the
// swizzled [kt][HW][32] layout (for V); =0 writes normal [c][HW].
// grid (800, 4, NB)
// ---------------------------------------------------------------------------
template<int TRANSPOSED>
__global__ __launch_bounds__(256) void dwconv2_k(
    const unsigned short* __restrict__ A, const float* __restrict__ w,
    unsigned short* __restrict__ out)
{
    __shared__ unsigned short xsh[64][152];   // [c][3 rows * 48 px]
    __shared__ unsigned short osh[32][72];
    const int t = threadIdx.x;
    const int tile = blockIdx.x;
    const int c0 = blockIdx.y * 64;
    const long b = blockIdx.z;
    const int n0 = tile * 32;
    const int y  = n0 / IMGW;
    const int x0 = n0 % IMGW;
    const unsigned short* Ab = A + b * SZB;

    for (int idx = t; idx < 1152; idx += 256) {
        int seg = idx % 6;
        int dy  = (idx / 6) % 3;
        int c   = idx / 18;
        int yy  = y + dy - 1;
        int gx  = x0 - 8 + seg * 8;
        us8 v = (us8){0, 0, 0, 0, 0, 0, 0, 0};
        if (yy >= 0 && yy < IMGW && gx >= 0 && gx + 7 < IMGW)
            v = *(const us8*)(Ab + (long)(c0 + c) * HW + yy * IMGW + gx);
        *(us8*)&xsh[c][dy * 48 + seg * 8] = v;
    }
    __syncthreads();

    const int c  = t >> 2;
    const int ng = t & 3;
    float wreg[9];
#pragma unroll
    for (int u = 0; u < 9; ++u) wreg[u] = w[(c0 + c) * 9 + u];
    float s[8];
#pragma unroll
    for (int p = 0; p < 8; ++p) s[p] = 0.f;
#pragma unroll
    for (int dy = 0; dy < 3; ++dy) {
        int base = dy * 48 + ng * 8;
        float r[10];
        r[0] = bf2f(xsh[c][base + 7]);
        us8 mid = *(const us8*)&xsh[c][base + 8];
#pragma unroll
        for (int u = 0; u < 8; ++u) r[1 + u] = bf2f(mid[u]);
        r[9] = bf2f(xsh[c][base + 16]);
        float w0 = wreg[dy * 3 + 0], w1 = wreg[dy * 3 + 1], w2 = wreg[dy * 3 + 2];
#pragma unroll
        for (int p = 0; p < 8; ++p)
            s[p] = fmaf(w0, r[p], fmaf(w1, r[p + 1], fmaf(w2, r[p + 2], s[p])));
    }

    if (!TRANSPOSED) {
        us8 o;
#pragma unroll
        for (int p = 0; p < 8; ++p) o[p] = f2bf(s[p]);
        *(us8*)(out + b * SZB + (long)(c0 + c) * HW + n0 + ng * 8) = o;
    } else {
#pragma unroll
        for (int p = 0; p < 8; ++p) osh[ng * 8 + p][c] = f2bf(s[p]);
        __syncthreads();
        int n2 = t >> 3;
        int c8 = (t & 7) * 8;
        us8 o = *(const us8*)&osh[n2][c8];
        int n  = n0 + n2;
        int cg = c0 + c8;
        int kt = cg >> 5;
        int g2 = (cg >> 3) & 3;
        int slot = g2 ^ ((n >> 1) & 3);
        *(us8*)(out + b * SZB + ((long)kt * HW + n) * 32 + slot * 8) = o;
    }
}

// ---------------------------------------------------------------------------
// gram via MFMA, direct global us8 frag loads (same k-slot map both operands).
// grid (8 chunks, 8 heads, NB)
// ---------------------------------------------------------------------------
__global__ __launch_bounds__(256) void gram_k(
    const unsigned short* __restrict__ q, const unsigned short* __restrict__ k,
    float* __restrict__ part_qk, float* __restrict__ part_sq_q,
    float* __restrict__ part_sq_k)
{
    __shared__ float Sred[4 * 1024];
    __shared__ float sqq_l[4][32];
    __shared__ float sqk_l[4][32];
    const int t  = threadIdx.x;
    const int l  = t & 63;
    const int wv = t >> 6;
    const int g  = l >> 4;
    const int ln = l & 15;
    const int chunk = blockIdx.x;
    const int h = blockIdx.y;
    const int b = blockIdx.z;

    f32x4 accS[2][2], accQ[2], accK[2];
#pragma unroll
    for (int i = 0; i < 2; ++i) {
        accQ[i] = (f32x4){0, 0, 0, 0};
        accK[i] = (f32x4){0, 0, 0, 0};
#pragma unroll
        for (int j = 0; j < 2; ++j) accS[i][j] = (f32x4){0, 0, 0, 0};
    }

    const unsigned short* qb = q + (long)b * SZB + (long)(h * 32) * HW;
    const unsigned short* kb = k + (long)b * SZB + (long)(h * 32) * HW;
    long nb = (long)chunk * 3200 + wv * 800;
    for (int s = 0; s < 25; ++s, nb += 32) {
        FragU aq[2], bk[2];
#pragma unroll
        for (int i = 0; i < 2; ++i)
            aq[i].o = *(const us8*)(qb + (long)(i * 16 + ln) * HW + nb + g * 8);
#pragma unroll
        for (int j = 0; j < 2; ++j)
            bk[j].o = *(const us8*)(kb + (long)(j * 16 + ln) * HW + nb + g * 8);
#pragma unroll
        for (int i = 0; i < 2; ++i)
#pragma unroll
            for (int j = 0; j < 2; ++j)
                accS[i][j] = __builtin_amdgcn_mfma_f32_16x16x32_bf16(
                    aq[i].s, bk[j].s, accS[i][j], 0, 0, 0);
#pragma unroll
        for (int i = 0; i < 2; ++i) {
            accQ[i] = __builtin_amdgcn_mfma_f32_16x16x32_bf16(
                aq[i].s, aq[i].s, accQ[i], 0, 0, 0);
            accK[i] = __builtin_amdgcn_mfma_f32_16x16x32_bf16(
                bk[i].s, bk[i].s, accK[i], 0, 0, 0);
        }
    }
#pragma unroll
    for (int i = 0; i < 2; ++i)
#pragma unroll
        for (int j = 0; j < 2; ++j)
#pragma unroll
            for (int r = 0; r < 4; ++r) {
                int row = i * 16 + g * 4 + r;
                int col = j * 16 + ln;
                Sred[wv * 1024 + row * 32 + col] = accS[i][j][r];
            }
#pragma unroll
    for (int i = 0; i < 2; ++i)
#pragma unroll
        for (int r = 0; r < 4; ++r)
            if (ln == g * 4 + r) {
                sqq_l[wv][i * 16 + g * 4 + r] = accQ[i][r];
                sqk_l[wv][i * 16 + g * 4 + r] = accK[i][r];
            }
    __syncthreads();
    const long pb = ((long)(b * NHEADS + h) * 8 + chunk);
#pragma unroll
    for (int e0 = 0; e0 < 4; ++e0) {
        int e = e0 * 256 + t;
        float v = Sred[e] + Sred[1024 + e] + Sred[2048 + e] + Sred[3072 + e];
        part_qk[pb * 1024 + e] = v;
    }
    if (t < 32)
        part_sq_q[pb * 32 + t] = sqq_l[0][t] + sqq_l[1][t] + sqq_l[2][t] + sqq_l[3][t];
    else if (t < 64) {
        int j = t - 32;
        part_sq_k[pb * 32 + j] = sqk_l[0][j] + sqk_l[1][j] + sqk_l[2][j] + sqk_l[3][j];
    }
}

// ---------------------------------------------------------------------------
// reduce -> normalize -> softmax -> W_eff = proj_w @ blockdiag(attn),
// stored in swizzled [b][kt=h][256][32] layout. grid 32 = (b,h)
// ---------------------------------------------------------------------------
__global__ __launch_bounds__(256) void attn_weff_k(
    const float* __restrict__ part_qk, const float* __restrict__ part_sq_q,
    const float* __restrict__ part_sq_k, const float* __restrict__ proj_w,
    const float* __restrict__ temp, unsigned short* __restrict__ weff_s)
{
    __shared__ float at[32 * 33];
    __shared__ float nq[32], nk[32];
    int bh = blockIdx.x;
    int b = bh >> 3, h = bh & 7;
    int t = threadIdx.x;
    long pb0 = (long)bh * 8;
    float4 s = make_float4(0, 0, 0, 0);
    for (int c = 0; c < 8; ++c) {
        float4 v = *(const float4*)(part_qk + (pb0 + c) * 1024 + t * 4);
        s.x += v.x; s.y += v.y; s.z += v.z; s.w += v.w;
    }
    if (t < 32) {
        float a = 0;
        for (int c = 0; c < 8; ++c) a += part_sq_q[(pb0 + c) * 32 + t];
        nq[t] = fmaxf(sqrtf(a), 1e-12f);
    } else if (t < 64) {
        int j = t - 32;
        float a = 0;
        for (int c = 0; c < 8; ++c) a += part_sq_k[(pb0 + c) * 32 + j];
        nk[j] = fmaxf(sqrtf(a), 1e-12f);
    }
    __syncthreads();
    float tp = temp[h];
    int ci = t >> 3, cj0 = (t & 7) * 4;
    at[ci * 33 + cj0 + 0] = s.x / (nq[ci] * nk[cj0 + 0]) * tp;
    at[ci * 33 + cj0 + 1] = s.y / (nq[ci] * nk[cj0 + 1]) * tp;
    at[ci * 33 + cj0 + 2] = s.z / (nq[ci] * nk[cj0 + 2]) * tp;
    at[ci * 33 + cj0 + 3] = s.w / (nq[ci] * nk[cj0 + 3]) * tp;
    __syncthreads();
    if (t < 32) {
        float m = -1e30f;
        for (int j = 0; j < 32; ++j) m = fmaxf(m, at[t * 33 + j]);
        float ss = 0;
        for (int j = 0; j < 32; ++j) {
            float e = expf(at[t * 33 + j] - m);
            at[t * 33 + j] = e;
            ss += e;
        }
        float inv = 1.f / ss;
        for (int j = 0; j < 32; ++j) at[t * 33 + j] *= inv;
    }
    __syncthreads();
    int co = t;
    float pw[32];
#pragma unroll
    for (int i2 = 0; i2 < 32; ++i2) pw[i2] = proj_w[(long)co * CDIM + h * 32 + i2];
    unsigned short* wb = weff_s + (long)b * 65536 + (long)h * (256 * 32) + co * 32;
    int swz = (co >> 1) & 3;
    for (int j = 0; j < 32; ++j) {
        float a = 0;
#pragma unroll
        for (int i2 = 0; i2 < 32; ++i2) a = fmaf(pw[i2], at[i2 * 33 + j], a);
        wb[((j >> 3) ^ swz) * 8 + (j & 7)] = f2bf(a);
    }
}

// ---------------------------------------------------------------------------
extern "C" void kernel_launch(void* const* d_in, const int* in_sizes, int n_in,
                              void* d_out, int out_size, void* d_ws, size_t ws_size,
                              hipStream_t stream)
{
    const float* low    = (const float*)d_in[0];
    const float* high   = (const float*)d_in[1];
    const float* q_w    = (const float*)d_in[2];
    const float* q_dw   = (const float*)d_in[3];
    const float* kv_w   = (const float*)d_in[4];
    const float* kv_dw  = (const float*)d_in[5];
    const float* proj_w = (const float*)d_in[6];
    const float* temp   = (const float*)d_in[7];
    float* out = (float*)d_out;

    // workspace (us = bf16 elems)
    unsigned short* usws = (unsigned short*)d_ws;
    unsigned short* XS   = usws;             // [4][8][HW][32]   4*SZB
    unsigned short* Areg = XS + 4 * SZB;     // [4][256][HW]     4*SZB
    unsigned short* VT   = Areg + 4 * SZB;   // [4][8][HW][32]   4*SZB
    unsigned short* wk_s = VT + 4 * SZB;     // [8][256][32]
    unsigned short* wv_s = wk_s + 65536;
    unsigned short* wq_s = wv_s + 65536;
    unsigned short* weff_s = wq_s + 65536;   // [4][8][256][32]
    float* part_qk   = (float*)(weff_s + 4L * 65536);
    float* part_sq_q = part_qk + 32L * 8 * 1024;
    float* part_sq_k = part_sq_q + 32L * 8 * 32;
    float* endp      = part_sq_k + 32L * 8 * 32;
    if (ws_size < (size_t)((char*)endp - (char*)d_ws)) return;

    // d_out as scratch: K_all then Q_all (bf16), consumed before final write
    unsigned short* K_all = (unsigned short*)d_out;           // [4][256][HW]
    unsigned short* Q_all = K_all + 4 * SZB;                  // [4][256][HW]

    dim3 blk(256);

    // weights -> swizzled bf16
    cvtw_k<<<dim3(32), blk, 0, stream>>>(kv_w, wk_s, 0, 256);
    cvtw_k<<<dim3(32), blk, 0, stream>>>(kv_w, wv_s, 256, 256);
    cvtw_k<<<dim3(32), blk, 0, stream>>>(q_w, wq_s, 0, 256);

    // low -> XS; k/v chains
    cvtT2_k<<<dim3(400, 4, NB), blk, 0, stream>>>(low, XS);
    gemm2_k<0><<<dim3(200, 2, NB), blk, 0, stream>>>(XS, wk_s, Areg,
                                                     SZB, 0, SZB, 256);
    dwconv2_k<0><<<dim3(800, 4, NB), blk, 0, stream>>>(Areg, kv_dw, K_all);
    gemm2_k<0><<<dim3(200, 2, NB), blk, 0, stream>>>(XS, wv_s, Areg,
                                                     SZB, 0, SZB, 256);
    dwconv2_k<1><<<dim3(800, 4, NB), blk, 0, stream>>>(Areg, kv_dw + 256 * 9, VT);

    // high -> XS; q chain
    cvtT2_k<<<dim3(400, 4, NB), blk, 0, stream>>>(high, XS);
    gemm2_k<0><<<dim3(200, 2, NB), blk, 0, stream>>>(XS, wq_s, Areg,
                                                     SZB, 0, SZB, 256);
    dwconv2_k<0><<<dim3(800, 4, NB), blk, 0, stream>>>(Areg, q_dw, Q_all);

    // gram + softmax + W_eff
    gram_k<<<dim3(8, NHEADS, NB), blk, 0, stream>>>(Q_all, K_all, part_qk,
                                                    part_sq_q, part_sq_k);
    attn_weff_k<<<dim3(32), blk, 0, stream>>>(
        part_qk, part_sq_q, part_sq_k, proj_w, temp, weff_s);

    // out[b] = W_eff[b] @ v[b]
    gemm2_k<1><<<dim3(200, 2, NB), blk, 0, stream>>>(VT, weff_s, out,
                                                     SZB, 65536, SZB, 256);
}

// Round 7
// 314.066 us; speedup vs baseline: 4.7966x; 1.3258x over previous
//
#include <hip/hip_runtime.h>
#include <math.h>

#define HW 25600
#define IMGW 160
#define CDIM 256
#define NB 4
#define NHEADS 8
#define SZB ((long)CDIM * HW)   // 6,553,600 elems

typedef __attribute__((ext_vector_type(8))) short short8v;
typedef __attribute__((ext_vector_type(4))) float f32x4;
typedef __attribute__((ext_vector_type(8))) unsigned short us8;

union FragU {
    us8 o;
    short8v s;
};

__device__ inline unsigned short f2bf(float f) {
    unsigned u = __float_as_uint(f);
    return (unsigned short)((u + 0x7fffu + ((u >> 16) & 1u)) >> 16);
}
__device__ inline float bf2f(unsigned short h) {
    return __uint_as_float(((unsigned)h) << 16);
}

// ---------------------------------------------------------------------------
// weights fp32 [co_off+co][256] -> swizzled bf16 [8kt][nco][32]
// slot(g2, co) = g2 ^ ((co>>1)&3)
// ---------------------------------------------------------------------------
__global__ __launch_bounds__(256) void cvtw_k(
    const float* __restrict__ w, unsigned short* __restrict__ o,
    int co_off, int nco)
{
    int idx = blockIdx.x * 256 + threadIdx.x;   // one us8 per thread
    if (idx >= nco * 32) return;
    int g2 = idx & 3;
    int kt = (idx >> 2) & 7;
    int co = idx >> 5;
    const float* src = w + (long)(co_off + co) * CDIM + kt * 32 + g2 * 8;
    us8 v;
#pragma unroll
    for (int u = 0; u < 8; ++u) v[u] = f2bf(src[u]);
    int slot = g2 ^ ((co >> 1) & 3);
    *(us8*)(o + ((long)kt * nco + co) * 32 + slot * 8) = v;
}

// ---------------------------------------------------------------------------
// fp32 [b][256][HW] -> swizzled-transposed bf16 XS [b][8kt][HW][32]
// grid (HW/64, 4, NB)
// ---------------------------------------------------------------------------
__global__ __launch_bounds__(256) void cvtT2_k(
    const float* __restrict__ x, unsigned short* __restrict__ xs)
{
    __shared__ float tile[64][65];
    const int t = threadIdx.x;
    const int n0 = blockIdx.x * 64;
    const int c0 = blockIdx.y * 64;
    const long b = blockIdx.z;
    const float* xb = x + b * SZB;
    unsigned short* xo = xs + b * SZB;
#pragma unroll
    for (int it = 0; it < 4; ++it) {
        int row = (t >> 4) + it * 16;     // c-local
        int col = (t & 15) * 4;           // n-local
        float4 v = *(const float4*)(xb + (long)(c0 + row) * HW + n0 + col);
        tile[row][col]     = v.x; tile[row][col + 1] = v.y;
        tile[row][col + 2] = v.z; tile[row][col + 3] = v.w;
    }
    __syncthreads();
#pragma unroll
    for (int jt = 0; jt < 2; ++jt) {
        int nl = (t >> 3) + jt * 32;
        int cl = (t & 7) * 8;
        us8 o;
#pragma unroll
        for (int u = 0; u < 8; ++u) o[u] = f2bf(tile[cl + u][nl]);
        int n  = n0 + nl;
        int c  = c0 + cl;
        int kt = c >> 5;
        int g2 = (c >> 3) & 3;
        int slot = g2 ^ ((n >> 1) & 3);
        *(us8*)(xo + ((long)kt * HW + n) * 32 + slot * 8) = o;
    }
}

// ---------------------------------------------------------------------------
// bf16 MFMA GEMM v2: out[b][co][n] = sum_k W[co][k] * X[k][n]
// Operands in swizzled [kt][row][32] layout; staged via global_load_lds
// width=16 into LINEAR LDS; frag reads apply the inverse swizzle (b128).
// 128x128 tile, 4 waves, 16x16x32 MFMA.
// ---------------------------------------------------------------------------
template<int OUTF32>
__global__ __launch_bounds__(256) void gemm2_k(
    const unsigned short* __restrict__ XS, const unsigned short* __restrict__ WS,
    void* __restrict__ outp, long xbs, long wbs, long obs, int nco)
{
    __shared__ __align__(16) unsigned short Wl[128 * 32];
    __shared__ __align__(16) unsigned short Xl[128 * 32];
    const int t  = threadIdx.x;
    const int l  = t & 63;
    const int wv = t >> 6;
    const int g  = l >> 4;
    const int ln = l & 15;
    const int n0  = blockIdx.x * 128;
    const int co0 = blockIdx.y * 128;
    const long b  = blockIdx.z;
    const unsigned short* Xb = XS + b * xbs;
    const unsigned short* Wb = WS + b * wbs;
    const int wr = wv >> 1, wc = wv & 1;

    f32x4 acc[4][4];
#pragma unroll
    for (int i = 0; i < 4; ++i)
#pragma unroll
        for (int j = 0; j < 4; ++j) acc[i][j] = (f32x4){0.f, 0.f, 0.f, 0.f};

    const int lrow = l >> 2;     // glds: lane covers row (instr*16 + lrow)
    const int lgrp = l & 3;      // 16B group

    for (int kt = 0; kt < 8; ++kt) {
        __syncthreads();
#pragma unroll
        for (int ii = 0; ii < 2; ++ii) {
            int instr = wv * 2 + ii;
            int row = instr * 16 + lrow;
            const unsigned short* wsrc =
                Wb + ((long)kt * nco + co0 + row) * 32 + lgrp * 8;
            __builtin_amdgcn_global_load_lds(
                (const __attribute__((address_space(1))) void*)wsrc,
                (__attribute__((address_space(3))) void*)&Wl[instr * 512], 16, 0, 0);
            const unsigned short* xsrc =
                Xb + ((long)kt * HW + n0 + row) * 32 + lgrp * 8;
            __builtin_amdgcn_global_load_lds(
                (const __attribute__((address_space(1))) void*)xsrc,
                (__attribute__((address_space(3))) void*)&Xl[instr * 512], 16, 0, 0);
        }
        __syncthreads();

        FragU A_[4], B_[4];
#pragma unroll
        for (int i = 0; i < 4; ++i) {
            int row = wr * 64 + i * 16 + ln;
            int slot = g ^ ((row >> 1) & 3);
            A_[i].o = *(const us8*)&Wl[row * 32 + slot * 8];
        }
#pragma unroll
        for (int j = 0; j < 4; ++j) {
            int row = wc * 64 + j * 16 + ln;
            int slot = g ^ ((row >> 1) & 3);
            B_[j].o = *(const us8*)&Xl[row * 32 + slot * 8];
        }
#pragma unroll
        for (int i = 0; i < 4; ++i)
#pragma unroll
            for (int j = 0; j < 4; ++j)
                acc[i][j] = __builtin_amdgcn_mfma_f32_16x16x32_bf16(
                    A_[i].s, B_[j].s, acc[i][j], 0, 0, 0);
    }

    // epilogue: D layout col=lane&15, row=(lane>>4)*4+reg (HW-verified)
    if (OUTF32) {
        float* ob = (float*)outp + b * obs;
#pragma unroll
        for (int i = 0; i < 4; ++i)
#pragma unroll
            for (int j = 0; j < 4; ++j) {
                long ocol = n0 + wc * 64 + j * 16 + ln;
#pragma unroll
                for (int r = 0; r < 4; ++r) {
                    long orow = co0 + wr * 64 + i * 16 + g * 4 + r;
                    ob[orow * HW + ocol] = acc[i][j][r];
                }
            }
    } else {
        unsigned short* ob = (unsigned short*)outp + b * obs;
#pragma unroll
        for (int i = 0; i < 4; ++i)
#pragma unroll
            for (int j = 0; j < 4; ++j) {
                long ocol = n0 + wc * 64 + j * 16 + ln;
#pragma unroll
                for (int r = 0; r < 4; ++r) {
                    long orow = co0 + wr * 64 + i * 16 + g * 4 + r;
                    ob[orow * HW + ocol] = f2bf(acc[i][j][r]);
                }
            }
    }
}

// ---------------------------------------------------------------------------
// depthwise 3x3 bf16, normal output [c][HW].
// Tile: 8 output rows x 160 px x 8 ch. Halo 10/8 rows = 1.25x fetch.
// grid (20, 32, NB)
// ---------------------------------------------------------------------------
__global__ __launch_bounds__(256) void dwK_k(
    const unsigned short* __restrict__ A, const float* __restrict__ w,
    unsigned short* __restrict__ out)
{
    __shared__ unsigned short xsh[8][10][168];
    const int t = threadIdx.x;
    const int y0 = blockIdx.x * 8;
    const int c0 = blockIdx.y * 8;
    const long b = blockIdx.z;
    const unsigned short* Ab = A + b * SZB;

    for (int idx = t; idx < 1600; idx += 256) {
        int seg = idx % 20;
        int row = (idx / 20) % 10;
        int ch  = idx / 200;
        int yy  = y0 + row - 1;
        us8 v = (us8){0, 0, 0, 0, 0, 0, 0, 0};
        if (yy >= 0 && yy < IMGW)
            v = *(const us8*)(Ab + (long)(c0 + ch) * HW + yy * IMGW + seg * 8);
        *(us8*)&xsh[ch][row][seg * 8] = v;
    }
    __syncthreads();

    const int ch = t >> 5;
    const int rem = t & 31;
    const int ro = rem >> 2;
    const int xq = rem & 3;
    float wreg[9];
#pragma unroll
    for (int u = 0; u < 9; ++u) wreg[u] = w[(c0 + ch) * 9 + u];
    unsigned short* ob = out + b * SZB + (long)(c0 + ch) * HW + (y0 + ro) * IMGW;

#pragma unroll
    for (int xs = 0; xs < 5; ++xs) {
        int x = xq * 8 + xs * 32;
        float s[8];
#pragma unroll
        for (int p = 0; p < 8; ++p) s[p] = 0.f;
#pragma unroll
        for (int dy = 0; dy < 3; ++dy) {
            const unsigned short* rp = &xsh[ch][ro + dy][0];
            float r[10];
            r[0] = (x > 0) ? bf2f(rp[x - 1]) : 0.f;
            us8 mid = *(const us8*)&rp[x];
#pragma unroll
            for (int u = 0; u < 8; ++u) r[1 + u] = bf2f(mid[u]);
            r[9] = (x + 8 < IMGW) ? bf2f(rp[x + 8]) : 0.f;
            float w0 = wreg[dy * 3], w1 = wreg[dy * 3 + 1], w2 = wreg[dy * 3 + 2];
#pragma unroll
            for (int p = 0; p < 8; ++p)
                s[p] = fmaf(w0, r[p], fmaf(w1, r[p + 1], fmaf(w2, r[p + 2], s[p])));
        }
        us8 o;
#pragma unroll
        for (int p = 0; p < 8; ++p) o[p] = f2bf(s[p]);
        *(us8*)(ob + x) = o;
    }
}

// ---------------------------------------------------------------------------
// depthwise 3x3 bf16, transposed+swizzled output [kt][HW][32] (for V).
// Tile: 4 output rows x 160 px x 16 ch. Halo 6/4 = 1.5x fetch.
// grid (40, 16, NB)
// ---------------------------------------------------------------------------
__global__ __launch_bounds__(256) void dwV_k(
    const unsigned short* __restrict__ A, const float* __restrict__ w,
    unsigned short* __restrict__ out)
{
    __shared__ unsigned short xsh[16][6][168];
    __shared__ unsigned short osh[640][17];
    const int t = threadIdx.x;
    const int y0 = blockIdx.x * 4;
    const int c0 = blockIdx.y * 16;
    const long b = blockIdx.z;
    const unsigned short* Ab = A + b * SZB;

    for (int idx = t; idx < 1920; idx += 256) {
        int seg = idx % 20;
        int row = (idx / 20) % 6;
        int ch  = idx / 120;
        int yy  = y0 + row - 1;
        us8 v = (us8){0, 0, 0, 0, 0, 0, 0, 0};
        if (yy >= 0 && yy < IMGW)
            v = *(const us8*)(Ab + (long)(c0 + ch) * HW + yy * IMGW + seg * 8);
        *(us8*)&xsh[ch][row][seg * 8] = v;
    }
    __syncthreads();

    {
        const int ch = t >> 4;
        const int rem = t & 15;
        const int ro = rem >> 2;
        const int xq = rem & 3;
        float wreg[9];
#pragma unroll
        for (int u = 0; u < 9; ++u) wreg[u] = w[(c0 + ch) * 9 + u];
#pragma unroll
        for (int xs = 0; xs < 5; ++xs) {
            int x = xq * 8 + xs * 32;
            float s[8];
#pragma unroll
            for (int p = 0; p < 8; ++p) s[p] = 0.f;
#pragma unroll
            for (int dy = 0; dy < 3; ++dy) {
                const unsigned short* rp = &xsh[ch][ro + dy][0];
                float r[10];
                r[0] = (x > 0) ? bf2f(rp[x - 1]) : 0.f;
                us8 mid = *(const us8*)&rp[x];
#pragma unroll
                for (int u = 0; u < 8; ++u) r[1 + u] = bf2f(mid[u]);
                r[9] = (x + 8 < IMGW) ? bf2f(rp[x + 8]) : 0.f;
                float w0 = wreg[dy * 3], w1 = wreg[dy * 3 + 1], w2 = wreg[dy * 3 + 2];
#pragma unroll
                for (int p = 0; p < 8; ++p)
                    s[p] = fmaf(w0, r[p], fmaf(w1, r[p + 1], fmaf(w2, r[p + 2], s[p])));
            }
            int nl = ro * IMGW + x;
#pragma unroll
            for (int p = 0; p < 8; ++p) osh[nl + p][ch] = f2bf(s[p]);
        }
    }
    __syncthreads();

    for (int idx = t; idx < 1280; idx += 256) {
        int nl = idx >> 1;
        int c8 = (idx & 1) * 8;
        us8 o;
#pragma unroll
        for (int u = 0; u < 8; ++u) o[u] = osh[nl][c8 + u];
        int n  = y0 * IMGW + nl;
        int cg = c0 + c8;
        int kt = cg >> 5;
        int g2 = (cg >> 3) & 3;
        int slot = g2 ^ ((n >> 1) & 3);
        *(us8*)(out + b * SZB + ((long)kt * HW + n) * 32 + slot * 8) = o;
    }
}

// ---------------------------------------------------------------------------
// gram via MFMA, direct global us8 frag loads (same k-slot map both operands).
// grid (8 chunks, 8 heads, NB)
// ---------------------------------------------------------------------------
__global__ __launch_bounds__(256) void gram_k(
    const unsigned short* __restrict__ q, const unsigned short* __restrict__ k,
    float* __restrict__ part_qk, float* __restrict__ part_sq_q,
    float* __restrict__ part_sq_k)
{
    __shared__ float Sred[4 * 1024];
    __shared__ float sqq_l[4][32];
    __shared__ float sqk_l[4][32];
    const int t  = threadIdx.x;
    const int l  = t & 63;
    const int wv = t >> 6;
    const int g  = l >> 4;
    const int ln = l & 15;
    const int chunk = blockIdx.x;
    const int h = blockIdx.y;
    const int b = blockIdx.z;

    f32x4 accS[2][2], accQ[2], accK[2];
#pragma unroll
    for (int i = 0; i < 2; ++i) {
        accQ[i] = (f32x4){0, 0, 0, 0};
        accK[i] = (f32x4){0, 0, 0, 0};
#pragma unroll
        for (int j = 0; j < 2; ++j) accS[i][j] = (f32x4){0, 0, 0, 0};
    }

    const unsigned short* qb = q + (long)b * SZB + (long)(h * 32) * HW;
    const unsigned short* kb = k + (long)b * SZB + (long)(h * 32) * HW;
    long nb = (long)chunk * 3200 + wv * 800;
    for (int s = 0; s < 25; ++s, nb += 32) {
        FragU aq[2], bk[2];
#pragma unroll
        for (int i = 0; i < 2; ++i)
            aq[i].o = *(const us8*)(qb + (long)(i * 16 + ln) * HW + nb + g * 8);
#pragma unroll
        for (int j = 0; j < 2; ++j)
            bk[j].o = *(const us8*)(kb + (long)(j * 16 + ln) * HW + nb + g * 8);
#pragma unroll
        for (int i = 0; i < 2; ++i)
#pragma unroll
            for (int j = 0; j < 2; ++j)
                accS[i][j] = __builtin_amdgcn_mfma_f32_16x16x32_bf16(
                    aq[i].s, bk[j].s, accS[i][j], 0, 0, 0);
#pragma unroll
        for (int i = 0; i < 2; ++i) {
            accQ[i] = __builtin_amdgcn_mfma_f32_16x16x32_bf16(
                aq[i].s, aq[i].s, accQ[i], 0, 0, 0);
            accK[i] = __builtin_amdgcn_mfma_f32_16x16x32_bf16(
                bk[i].s, bk[i].s, accK[i], 0, 0, 0);
        }
    }
#pragma unroll
    for (int i = 0; i < 2; ++i)
#pragma unroll
        for (int j = 0; j < 2; ++j)
#pragma unroll
            for (int r = 0; r < 4; ++r) {
                int row = i * 16 + g * 4 + r;
                int col = j * 16 + ln;
                Sred[wv * 1024 + row * 32 + col] = accS[i][j][r];
            }
#pragma unroll
    for (int i = 0; i < 2; ++i)
#pragma unroll
        for (int r = 0; r < 4; ++r)
            if (ln == g * 4 + r) {
                sqq_l[wv][i * 16 + g * 4 + r] = accQ[i][r];
                sqk_l[wv][i * 16 + g * 4 + r] = accK[i][r];
            }
    __syncthreads();
    const long pb = ((long)(b * NHEADS + h) * 8 + chunk);
#pragma unroll
    for (int e0 = 0; e0 < 4; ++e0) {
        int e = e0 * 256 + t;
        float v = Sred[e] + Sred[1024 + e] + Sred[2048 + e] + Sred[3072 + e];
        part_qk[pb * 1024 + e] = v;
    }
    if (t < 32)
        part_sq_q[pb * 32 + t] = sqq_l[0][t] + sqq_l[1][t] + sqq_l[2][t] + sqq_l[3][t];
    else if (t < 64) {
        int j = t - 32;
        part_sq_k[pb * 32 + j] = sqk_l[0][j] + sqk_l[1][j] + sqk_l[2][j] + sqk_l[3][j];
    }
}

// ---------------------------------------------------------------------------
// reduce -> normalize -> softmax -> W_eff = proj_w @ blockdiag(attn),
// stored in swizzled [b][kt=h][256][32] layout. grid 32 = (b,h)
// ---------------------------------------------------------------------------
__global__ __launch_bounds__(256) void attn_weff_k(
    const float* __restrict__ part_qk, const float* __restrict__ part_sq_q,
    const float* __restrict__ part_sq_k, const float* __restrict__ proj_w,
    const float* __restrict__ temp, unsigned short* __restrict__ weff_s)
{
    __shared__ float at[32 * 33];
    __shared__ float nq[32], nk[32];
    int bh = blockIdx.x;
    int b = bh >> 3, h = bh & 7;
    int t = threadIdx.x;
    long pb0 = (long)bh * 8;
    float4 s = make_float4(0, 0, 0, 0);
    for (int c = 0; c < 8; ++c) {
        float4 v = *(const float4*)(part_qk + (pb0 + c) * 1024 + t * 4);
        s.x += v.x; s.y += v.y; s.z += v.z; s.w += v.w;
    }
    if (t < 32) {
        float a = 0;
        for (int c = 0; c < 8; ++c) a += part_sq_q[(pb0 + c) * 32 + t];
        nq[t] = fmaxf(sqrtf(a), 1e-12f);
    } else if (t < 64) {
        int j = t - 32;
        float a = 0;
        for (int c = 0; c < 8; ++c) a += part_sq_k[(pb0 + c) * 32 + j];
        nk[j] = fmaxf(sqrtf(a), 1e-12f);
    }
    __syncthreads();
    float tp = temp[h];
    int ci = t >> 3, cj0 = (t & 7) * 4;
    at[ci * 33 + cj0 + 0] = s.x / (nq[ci] * nk[cj0 + 0]) * tp;
    at[ci * 33 + cj0 + 1] = s.y / (nq[ci] * nk[cj0 + 1]) * tp;
    at[ci * 33 + cj0 + 2] = s.z / (nq[ci] * nk[cj0 + 2]) * tp;
    at[ci * 33 + cj0 + 3] = s.w / (nq[ci] * nk[cj0 + 3]) * tp;
    __syncthreads();
    if (t < 32) {
        float m = -1e30f;
        for (int j = 0; j < 32; ++j) m = fmaxf(m, at[t * 33 + j]);
        float ss = 0;
        for (int j = 0; j < 32; ++j) {
            float e = expf(at[t * 33 + j] - m);
            at[t * 33 + j] = e;
            ss += e;
        }
        float inv = 1.f / ss;
        for (int j = 0; j < 32; ++j) at[t * 33 + j] *= inv;
    }
    __syncthreads();
    int co = t;
    float pw[32];
#pragma unroll
    for (int i2 = 0; i2 < 32; ++i2) pw[i2] = proj_w[(long)co * CDIM + h * 32 + i2];
    unsigned short* wb = weff_s + (long)b * 65536 + (long)h * (256 * 32) + co * 32;
    int swz = (co >> 1) & 3;
    for (int j = 0; j < 32; ++j) {
        float a = 0;
#pragma unroll
        for (int i2 = 0; i2 < 32; ++i2) a = fmaf(pw[i2], at[i2 * 33 + j], a);
        wb[((j >> 3) ^ swz) * 8 + (j & 7)] = f2bf(a);
    }
}

// ---------------------------------------------------------------------------
extern "C" void kernel_launch(void* const* d_in, const int* in_sizes, int n_in,
                              void* d_out, int out_size, void* d_ws, size_t ws_size,
                              hipStream_t stream)
{
    const float* low    = (const float*)d_in[0];
    const float* high   = (const float*)d_in[1];
    const float* q_w    = (const float*)d_in[2];
    const float* q_dw   = (const float*)d_in[3];
    const float* kv_w   = (const float*)d_in[4];
    const float* kv_dw  = (const float*)d_in[5];
    const float* proj_w = (const float*)d_in[6];
    const float* temp   = (const float*)d_in[7];
    float* out = (float*)d_out;

    // workspace (bf16 elems)
    unsigned short* usws = (unsigned short*)d_ws;
    unsigned short* XS   = usws;             // [4][8][HW][32]   4*SZB
    unsigned short* Areg = XS + 4 * SZB;     // [4][256][HW]     4*SZB
    unsigned short* VT   = Areg + 4 * SZB;   // [4][8][HW][32]   4*SZB
    unsigned short* wk_s = VT + 4 * SZB;     // [8][256][32]
    unsigned short* wv_s = wk_s + 65536;
    unsigned short* wq_s = wv_s + 65536;
    unsigned short* weff_s = wq_s + 65536;   // [4][8][256][32]
    float* part_qk   = (float*)(weff_s + 4L * 65536);
    float* part_sq_q = part_qk + 32L * 8 * 1024;
    float* part_sq_k = part_sq_q + 32L * 8 * 32;
    float* endp      = part_sq_k + 32L * 8 * 32;
    if (ws_size < (size_t)((char*)endp - (char*)d_ws)) return;

    // d_out as scratch: K_all then Q_all (bf16), consumed before final write
    unsigned short* K_all = (unsigned short*)d_out;           // [4][256][HW]
    unsigned short* Q_all = K_all + 4 * SZB;                  // [4][256][HW]

    dim3 blk(256);

    // weights -> swizzled bf16
    cvtw_k<<<dim3(32), blk, 0, stream>>>(kv_w, wk_s, 0, 256);
    cvtw_k<<<dim3(32), blk, 0, stream>>>(kv_w, wv_s, 256, 256);
    cvtw_k<<<dim3(32), blk, 0, stream>>>(q_w, wq_s, 0, 256);

    // low -> XS; k/v chains
    cvtT2_k<<<dim3(400, 4, NB), blk, 0, stream>>>(low, XS);
    gemm2_k<0><<<dim3(200, 2, NB), blk, 0, stream>>>(XS, wk_s, Areg,
                                                     SZB, 0, SZB, 256);
    dwK_k<<<dim3(20, 32, NB), blk, 0, stream>>>(Areg, kv_dw, K_all);
    gemm2_k<0><<<dim3(200, 2, NB), blk, 0, stream>>>(XS, wv_s, Areg,
                                                     SZB, 0, SZB, 256);
    dwV_k<<<dim3(40, 16, NB), blk, 0, stream>>>(Areg, kv_dw + 256 * 9, VT);

    // high -> XS; q chain
    cvtT2_k<<<dim3(400, 4, NB), blk, 0, stream>>>(high, XS);
    gemm2_k<0><<<dim3(200, 2, NB), blk, 0, stream>>>(XS, wq_s, Areg,
                                                     SZB, 0, SZB, 256);
    dwK_k<<<dim3(20, 32, NB), blk, 0, stream>>>(Areg, q_dw, Q_all);

    // gram + softmax + W_eff
    gram_k<<<dim3(8, NHEADS, NB), blk, 0, stream>>>(Q_all, K_all, part_qk,
                                                    part_sq_q, part_sq_k);
    attn_weff_k<<<dim3(32), blk, 0, stream>>>(
        part_qk, part_sq_q, part_sq_k, proj_w, temp, weff_s);

    // out[b] = W_eff[b] @ v[b]
    gemm2_k<1><<<dim3(200, 2, NB), blk, 0, stream>>>(VT, weff_s, out,
                                                     SZB, 65536, SZB, 256);
}